// Round 8
// baseline (243.520 us; speedup 1.0000x reference)
//
#include <hip/hip_runtime.h>
#include <hip/hip_bf16.h>

#define NQ 2048
#define NB 2

typedef unsigned short u16;
typedef unsigned int u32;
typedef _Float16 f16;
typedef __attribute__((ext_vector_type(8))) _Float16 half8;
typedef __attribute__((ext_vector_type(2))) __fp16 fp16x2;
typedef __attribute__((ext_vector_type(4))) float f32x4;

#define MFMAH(A, B, C) __builtin_amdgcn_mfma_f32_16x16x32_f16(A, B, C, 0, 0, 0)

__device__ __forceinline__ u16 f2h(float x) {
    f16 h = (f16)x;                 // v_cvt_f16_f32 (RNE)
    return *(u16*)&h;
}
// packed f32x2 -> fp16x2 (v_cvt_pkrtz_f16_f32), returned as u32
__device__ __forceinline__ u32 pk_h2(float a, float b) {
    union { fp16x2 v; u32 u; } c;
    c.v = __builtin_amdgcn_cvt_pkrtz(a, b);
    return c.u;
}
// raw v_exp_f32 (2^x)
__device__ __forceinline__ float fexp2(float x) {
#if __has_builtin(__builtin_amdgcn_exp2f)
    return __builtin_amdgcn_exp2f(x);
#else
    return exp2f(x);
#endif
}
// async global->LDS DMA, 16B/lane; lds dest is wave-uniform base + lane*16
__device__ __forceinline__ void glds16(const u16* g, u16* l) {
    typedef const __attribute__((address_space(1))) u16 gu16;
    typedef __attribute__((address_space(3))) u16 lu16;
    __builtin_amdgcn_global_load_lds((gu16*)g, (lu16*)l, 16, 0, 0);
}

// q-scale: 1/sqrt(64) * log2(e), so attention scores land in log2 domain
#define QSCALE 0.18033688011112042f

// ============ merge to fp16: rows 0..3071 = q,k,v; 3072..4095 = o ============
__global__ __launch_bounds__(256) void merge_w16(
    const float* __restrict__ w0, const float* __restrict__ dw0, const float* __restrict__ db0,
    const float* __restrict__ w1, const float* __restrict__ dw1, const float* __restrict__ db1,
    const float* __restrict__ w2, const float* __restrict__ dw2, const float* __restrict__ db2,
    const float* __restrict__ w3, const float* __restrict__ dw3, const float* __restrict__ db3,
    u16* __restrict__ Wf) {
    int idx = blockIdx.x * 256 + threadIdx.x;     // over 4096*1024
    int row = idx >> 10, col = idx & 1023;
    int which = row >> 10, lr = row & 1023;
    const float* W  = (which == 0) ? w0  : (which == 1) ? w1  : (which == 2) ? w2  : w3;
    const float* dW = (which == 0) ? dw0 : (which == 1) ? dw1 : (which == 2) ? dw2 : dw3;
    const float* dB = (which == 0) ? db0 : (which == 1) ? db1 : (which == 2) ? db2 : db3;
    float acc = W[lr * 1024 + col];
#pragma unroll
    for (int r = 0; r < 5; ++r) acc += dB[lr * 5 + r] * dW[r * 1024 + col];
    if (which == 0) acc *= QSCALE;
    Wf[idx] = f2h(acc);
}

__global__ __launch_bounds__(256) void bias_pack(
    const float* __restrict__ b0, const float* __restrict__ b1,
    const float* __restrict__ b2, const float* __restrict__ b3,
    float* __restrict__ ball) {
    int t = blockIdx.x * 256 + threadIdx.x;   // 4096
    int which = t >> 10;
    const float* B = (which == 0) ? b0 : (which == 1) ? b1 : (which == 2) ? b2 : b3;
    float v = B[t & 1023];
    if (which == 0) v *= QSCALE;
    ball[t] = v;
}

// x -> single fp16 (RNE)
__global__ __launch_bounds__(256) void xcast(const float* __restrict__ x,
                                             u16* __restrict__ xf) {
    int i4 = (blockIdx.x * 256 + threadIdx.x) * 4;
    float4 v = *(const float4*)&x[i4];
    *(uint2*)&xf[i4] = make_uint2(pk_h2(v.x, v.y), pk_h2(v.z, v.w));
}

// ============ fp16 GEMM: C[4096][N] = A @ B^T + bias ============
// Single fp16 product. TM x 128 tile, BK=64 staged as two 32-col halves
// (each half keeps the packed [row][32] m97 bank layout), global_load_lds(16).
// If VtOut: column blocks bn >= 2048 (V third of fused QKV) store TRANSPOSED
// to VtOut[(col-2048)][4096].
template <int TM>
__global__ __launch_bounds__(256) void gemm_f16(
    const u16* __restrict__ Af, const u16* __restrict__ Bf,
    const float* __restrict__ bias,
    float* __restrict__ Cf, u16* __restrict__ Cb, int ldc,
    u16* __restrict__ VtOut) {
    constexpr int MI = TM / 32;               // m-subtiles per wave
    __shared__ u16 As[2][TM * 32];
    __shared__ u16 Bs[2][128 * 32];
    const int tid = threadIdx.x;
    const int wid = tid >> 6, lane = tid & 63;
    const int ln = lane & 15, quad = lane >> 4;
    const int bm = blockIdx.y * TM, bn = blockIdx.x * 128;
    const int wm = (wid >> 1) * (TM / 2), wn = (wid & 1) * 64;
    const int lrow = lane >> 2;               // DMA: row within 16-row group
    const int lchunk = (lane & 3) * 8;        // DMA: u16 offset of 16B chunk

    f32x4 acc[MI][4];
#pragma unroll
    for (int i = 0; i < MI; ++i)
#pragma unroll
        for (int j = 0; j < 4; ++j) acc[i][j] = (f32x4){0.f, 0.f, 0.f, 0.f};

    for (int k0 = 0; k0 < 1024; k0 += 64) {
#pragma unroll
        for (int hf = 0; hf < 2; ++hf) {
#pragma unroll
            for (int p = 0; p < TM / 64; ++p) {
                int r = p * 64 + wid * 16;
                glds16(&Af[(bm + r + lrow) * 1024 + k0 + hf * 32 + lchunk],
                       &As[hf][r * 32]);
            }
#pragma unroll
            for (int p = 0; p < 2; ++p) {
                int r = p * 64 + wid * 16;
                glds16(&Bf[(bn + r + lrow) * 1024 + k0 + hf * 32 + lchunk],
                       &Bs[hf][r * 32]);
            }
        }
        asm volatile("s_waitcnt vmcnt(0)" ::: "memory");
        __syncthreads();

        half8 a[MI][2], b[4][2];
#pragma unroll
        for (int kc = 0; kc < 2; ++kc) {
#pragma unroll
            for (int j = 0; j < 4; ++j)
                b[j][kc] = *(const half8*)&Bs[kc][(wn + j * 16 + ln) * 32 + quad * 8];
#pragma unroll
            for (int i = 0; i < MI; ++i)
                a[i][kc] = *(const half8*)&As[kc][(wm + i * 16 + ln) * 32 + quad * 8];
        }
#pragma unroll
        for (int i = 0; i < MI; ++i)
#pragma unroll
            for (int j = 0; j < 4; ++j) {
                acc[i][j] = MFMAH(a[i][0], b[j][0], acc[i][j]);
                acc[i][j] = MFMAH(a[i][1], b[j][1], acc[i][j]);
            }
        __syncthreads();
    }

    if (VtOut && bn >= 2048) {
        // transposed store: VtOut[d][seq]; lane holds 4 consecutive seq rows.
#pragma unroll
        for (int i = 0; i < MI; ++i)
#pragma unroll
            for (int j = 0; j < 4; ++j) {
                int col = bn + wn + j * 16 + ln;
                float bv = bias[col];
                int colV = col - 2048;
                int row0 = bm + wm + i * 16 + quad * 4;
                ushort4 pk = make_ushort4(f2h(acc[i][j][0] + bv), f2h(acc[i][j][1] + bv),
                                          f2h(acc[i][j][2] + bv), f2h(acc[i][j][3] + bv));
                *(ushort4*)&VtOut[colV * 4096 + row0] = pk;
            }
        return;
    }

#pragma unroll
    for (int i = 0; i < MI; ++i)
#pragma unroll
        for (int j = 0; j < 4; ++j) {
            int col = bn + wn + j * 16 + ln;
            float bv = bias[col];
#pragma unroll
            for (int r = 0; r < 4; ++r) {
                int row = bm + wm + i * 16 + quad * 4 + r;
                float v = acc[i][j][r] + bv;
                if (Cb) Cb[row * ldc + col] = f2h(v);
                else    Cf[row * ldc + col] = v;
            }
        }
}

// ============ flash attention, fp16 MFMA, transposed S/O, DMA-staged ============
// Block: 4 waves x 32 q-rows = 128 q of one (b,h). 64-key tiles, double-buffered
// via global_load_lds into packed split-half LDS (m97 bank layout, DMA-legal):
//   Ks[buf][d-half][key][32], Vs[buf][key-half][d][32].
// One barrier/tile. Scores arrive in log2 domain (q pre-scaled by log2e/8),
// so p = v_exp_f32(s) raw. Row sums via ones-MFMA.
__global__ __launch_bounds__(256) void flash_f16(
    const u16* __restrict__ QKV, const u16* __restrict__ Vt,
    u16* __restrict__ AO) {
    __shared__ u16 Ks[2][2][64 * 32];
    __shared__ u16 Vs[2][2][64 * 32];
    __shared__ u16 Ps[4][32 * 72];     // per-wave [qrow][key], stride 72

    const int tid = threadIdx.x;
    const int wid = tid >> 6, lane = tid & 63;
    const int ln = lane & 15, quad = lane >> 4;
    const int qt = blockIdx.x, h = blockIdx.y, b = blockIdx.z;
    const int rowbase = b * NQ;
    const int col0 = h * 64;
    const int q0 = rowbase + qt * 128 + wid * 32;
    const int drow = lane >> 2;          // DMA: row within 16-row group
    const int dchunk = (lane & 3) * 8;   // DMA: u16 offset of 16B chunk

    const half8 ones = {(f16)1, (f16)1, (f16)1, (f16)1,
                        (f16)1, (f16)1, (f16)1, (f16)1};

    // Q fragments (B-operand: lane ln = q-row q0+mi*16+ln, k = kc*32+quad*8+j)
    half8 qf[2][2];
#pragma unroll
    for (int mi = 0; mi < 2; ++mi)
#pragma unroll
        for (int kc = 0; kc < 2; ++kc)
            qf[mi][kc] = *(const half8*)&QKV[(q0 + mi * 16 + ln) * 3072 + col0 +
                                             kc * 32 + quad * 8];

    f32x4 accO[4][2];    // [a: d-subtile][mi], element (d=a*16+quad*4+r, q=mi*16+ln)
    f32x4 accS[2];       // row sums, col = q = ln
#pragma unroll
    for (int mi = 0; mi < 2; ++mi) {
        accS[mi] = (f32x4){0.f, 0.f, 0.f, 0.f};
#pragma unroll
        for (int a = 0; a < 4; ++a) accO[a][mi] = (f32x4){0.f, 0.f, 0.f, 0.f};
    }

    const int NT = NQ / 64;

    // DMA stage of one 64-key tile: wave wid covers rows [wid*16, wid*16+16)
#define STAGE(buf, kt)                                                                 \
    {                                                                                  \
        int ktbase = rowbase + (kt) * 64;                                              \
        _Pragma("unroll")                                                              \
        for (int hf = 0; hf < 2; ++hf)                                                 \
            glds16(&QKV[(ktbase + wid * 16 + drow) * 3072 + 1024 + col0 + hf * 32 +    \
                        dchunk],                                                       \
                   &Ks[buf][hf][wid * 16 * 32]);                                       \
        _Pragma("unroll")                                                              \
        for (int kh = 0; kh < 2; ++kh)                                                 \
            glds16(&Vt[(col0 + wid * 16 + drow) * 4096 + ktbase + kh * 32 + dchunk],   \
                   &Vs[buf][kh][wid * 16 * 32]);                                       \
    }

    STAGE(0, 0)
    asm volatile("s_waitcnt vmcnt(0)" ::: "memory");
    __syncthreads();

    for (int kt = 0; kt < NT; ++kt) {
        const int cur = kt & 1;
        if (kt + 1 < NT) STAGE(cur ^ 1, kt + 1)

        // S^T = K @ Q^T : element (key = a*16+quad*4+r, q = mi*16+ln)
        f32x4 s[4][2];
#pragma unroll
        for (int a = 0; a < 4; ++a) {
            half8 kf0 = *(const half8*)&Ks[cur][0][(a * 16 + ln) * 32 + quad * 8];
            half8 kf1 = *(const half8*)&Ks[cur][1][(a * 16 + ln) * 32 + quad * 8];
#pragma unroll
            for (int mi = 0; mi < 2; ++mi) {
                f32x4 t = (f32x4){0.f, 0.f, 0.f, 0.f};
                t = MFMAH(kf0, qf[mi][0], t);
                t = MFMAH(kf1, qf[mi][1], t);
                s[a][mi] = t;
            }
        }

        // p = 2^s: 4 consecutive keys per lane -> one 8B LDS write each
#pragma unroll
        for (int mi = 0; mi < 2; ++mi)
#pragma unroll
            for (int a = 0; a < 4; ++a) {
                float p0 = fexp2(s[a][mi][0]), p1 = fexp2(s[a][mi][1]);
                float p2 = fexp2(s[a][mi][2]), p3 = fexp2(s[a][mi][3]);
                uint2 w = make_uint2(pk_h2(p0, p1), pk_h2(p2, p3));
                *(uint2*)&Ps[wid][(mi * 16 + ln) * 72 + a * 16 + quad * 4] = w;
            }

        asm volatile("s_waitcnt lgkmcnt(0)" ::: "memory");   // P visible wave-wide

        // P fragments (B-operand) + row sums via ones-MFMA (A=ones)
        half8 pf[2][2];
#pragma unroll
        for (int mi = 0; mi < 2; ++mi)
#pragma unroll
            for (int kc = 0; kc < 2; ++kc) {
                pf[mi][kc] = *(const half8*)&Ps[wid][(mi * 16 + ln) * 72 +
                                                     kc * 32 + quad * 8];
                accS[mi] = MFMAH(ones, pf[mi][kc], accS[mi]);
            }

        // O^T += V^T @ P^T : element (d = a*16+quad*4+r, q = mi*16+ln)
#pragma unroll
        for (int a = 0; a < 4; ++a) {
            half8 vf0 = *(const half8*)&Vs[cur][0][(a * 16 + ln) * 32 + quad * 8];
            half8 vf1 = *(const half8*)&Vs[cur][1][(a * 16 + ln) * 32 + quad * 8];
#pragma unroll
            for (int mi = 0; mi < 2; ++mi) {
                accO[a][mi] = MFMAH(vf0, pf[mi][0], accO[a][mi]);
                accO[a][mi] = MFMAH(vf1, pf[mi][1], accO[a][mi]);
            }
        }

        asm volatile("s_waitcnt vmcnt(0)" ::: "memory");   // next-tile DMA done
        __syncthreads();
    }

    // epilogue: normalize (inv uniform per lane), single fp16 AO, ushort4 stores
#pragma unroll
    for (int mi = 0; mi < 2; ++mi) {
        float inv = 1.f / accS[mi][0];
        int q = q0 + mi * 16 + ln;
#pragma unroll
        for (int a = 0; a < 4; ++a) {
            ushort4 pk = make_ushort4(f2h(accO[a][mi][0] * inv),
                                      f2h(accO[a][mi][1] * inv),
                                      f2h(accO[a][mi][2] * inv),
                                      f2h(accO[a][mi][3] * inv));
            *(ushort4*)&AO[q * 1024 + col0 + a * 16 + quad * 4] = pk;
        }
    }
#undef STAGE
}

// ============ launch ============
extern "C" void kernel_launch(void* const* d_in, const int* in_sizes, int n_in,
                              void* d_out, int out_size, void* d_ws, size_t ws_size,
                              hipStream_t stream) {
    const float* x = (const float*)d_in[0];
    const float* w[4]  = {(const float*)d_in[1],  (const float*)d_in[5],
                          (const float*)d_in[9],  (const float*)d_in[13]};
    const float* bv[4] = {(const float*)d_in[2],  (const float*)d_in[6],
                          (const float*)d_in[10], (const float*)d_in[14]};
    const float* dw[4] = {(const float*)d_in[3],  (const float*)d_in[7],
                          (const float*)d_in[11], (const float*)d_in[15]};
    const float* db[4] = {(const float*)d_in[4],  (const float*)d_in[8],
                          (const float*)d_in[12], (const float*)d_in[16]};

    u16* p = (u16*)d_ws;
    u16* Wf  = p; p += 4096 * 1024;
    u16* xf  = p; p += 4096 * 1024;
    u16* QKV = p; p += 4096 * 3072;   // V third unused (lives in Vt)
    u16* Vt  = p; p += 1024 * 4096;
    float* ball = (float*)p;          // 4096 floats
    // AO aliases xf: x is dead after the QKV GEMM completes (same stream).
    u16* AO = xf;

    merge_w16<<<16384, 256, 0, stream>>>(w[0], dw[0], db[0], w[1], dw[1], db[1],
                                         w[2], dw[2], db[2], w[3], dw[3], db[3], Wf);
    bias_pack<<<16, 256, 0, stream>>>(bv[0], bv[1], bv[2], bv[3], ball);
    xcast<<<4096, 256, 0, stream>>>(x, xf);

    // fused q,k,v projection: q,k -> QKV fp16 row-major; v -> Vt transposed
    gemm_f16<128><<<dim3(24, 32), 256, 0, stream>>>(xf, Wf, ball,
                                                    nullptr, QKV, 3072, Vt);

    flash_f16<<<dim3(NQ / 128, 16, NB), 256, 0, stream>>>(QKV, Vt, AO);

    // o projection: fp32 out, TM=64 -> 512 blocks (2 blocks/CU)
    gemm_f16<64><<<dim3(8, 64), 256, 0, stream>>>(AO, Wf + 3072 * 1024,
                                                  ball + 3072, (float*)d_out, nullptr, 1024,
                                                  nullptr);
}

// Round 9
// 225.616 us; speedup vs baseline: 1.0794x; 1.0794x over previous
//
#include <hip/hip_runtime.h>
#include <hip/hip_bf16.h>

#define NQ 2048
#define NB 2

typedef unsigned short u16;
typedef unsigned int u32;
typedef _Float16 f16;
typedef __attribute__((ext_vector_type(8))) _Float16 half8;
typedef __attribute__((ext_vector_type(2))) __fp16 fp16x2;
typedef __attribute__((ext_vector_type(4))) float f32x4;

#define MFMAH(A, B, C) __builtin_amdgcn_mfma_f32_16x16x32_f16(A, B, C, 0, 0, 0)

__device__ __forceinline__ u16 f2h(float x) {
    f16 h = (f16)x;                 // v_cvt_f16_f32 (RNE)
    return *(u16*)&h;
}
// packed f32x2 -> fp16x2 (v_cvt_pkrtz_f16_f32), returned as u32
__device__ __forceinline__ u32 pk_h2(float a, float b) {
    union { fp16x2 v; u32 u; } c;
    c.v = __builtin_amdgcn_cvt_pkrtz(a, b);
    return c.u;
}
// raw v_exp_f32 (2^x)
__device__ __forceinline__ float fexp2(float x) {
#if __has_builtin(__builtin_amdgcn_exp2f)
    return __builtin_amdgcn_exp2f(x);
#else
    return exp2f(x);
#endif
}
// async global->LDS DMA, 16B/lane; lds dest is wave-uniform base + lane*16
__device__ __forceinline__ void glds16(const u16* g, u16* l) {
    typedef const __attribute__((address_space(1))) u16 gu16;
    typedef __attribute__((address_space(3))) u16 lu16;
    __builtin_amdgcn_global_load_lds((gu16*)g, (lu16*)l, 16, 0, 0);
}

// q-scale: 1/sqrt(64) * log2(e), so attention scores land in log2 domain
#define QSCALE 0.18033688011112042f

// ============ merge to fp16: rows 0..3071 = q,k,v; 3072..4095 = o ============
__global__ __launch_bounds__(256) void merge_w16(
    const float* __restrict__ w0, const float* __restrict__ dw0, const float* __restrict__ db0,
    const float* __restrict__ w1, const float* __restrict__ dw1, const float* __restrict__ db1,
    const float* __restrict__ w2, const float* __restrict__ dw2, const float* __restrict__ db2,
    const float* __restrict__ w3, const float* __restrict__ dw3, const float* __restrict__ db3,
    u16* __restrict__ Wf) {
    int idx = blockIdx.x * 256 + threadIdx.x;     // over 4096*1024
    int row = idx >> 10, col = idx & 1023;
    int which = row >> 10, lr = row & 1023;
    const float* W  = (which == 0) ? w0  : (which == 1) ? w1  : (which == 2) ? w2  : w3;
    const float* dW = (which == 0) ? dw0 : (which == 1) ? dw1 : (which == 2) ? dw2 : dw3;
    const float* dB = (which == 0) ? db0 : (which == 1) ? db1 : (which == 2) ? db2 : db3;
    float acc = W[lr * 1024 + col];
#pragma unroll
    for (int r = 0; r < 5; ++r) acc += dB[lr * 5 + r] * dW[r * 1024 + col];
    if (which == 0) acc *= QSCALE;
    Wf[idx] = f2h(acc);
}

__global__ __launch_bounds__(256) void bias_pack(
    const float* __restrict__ b0, const float* __restrict__ b1,
    const float* __restrict__ b2, const float* __restrict__ b3,
    float* __restrict__ ball) {
    int t = blockIdx.x * 256 + threadIdx.x;   // 4096
    int which = t >> 10;
    const float* B = (which == 0) ? b0 : (which == 1) ? b1 : (which == 2) ? b2 : b3;
    float v = B[t & 1023];
    if (which == 0) v *= QSCALE;
    ball[t] = v;
}

// x -> single fp16 (RNE)
__global__ __launch_bounds__(256) void xcast(const float* __restrict__ x,
                                             u16* __restrict__ xf) {
    int i4 = (blockIdx.x * 256 + threadIdx.x) * 4;
    float4 v = *(const float4*)&x[i4];
    *(uint2*)&xf[i4] = make_uint2(pk_h2(v.x, v.y), pk_h2(v.z, v.w));
}

// ============ fp16 GEMM: C[4096][N] = A @ B^T + bias ============
// Single fp16 product. TM x 128 tile, BK=64 staged as two 32-col halves
// (each half keeps the packed [row][32] m97 bank layout), global_load_lds(16).
// If VtOut: column blocks bn >= 2048 (V third of fused QKV) store TRANSPOSED
// to VtOut[(col-2048)][4096].
template <int TM>
__global__ __launch_bounds__(256) void gemm_f16(
    const u16* __restrict__ Af, const u16* __restrict__ Bf,
    const float* __restrict__ bias,
    float* __restrict__ Cf, u16* __restrict__ Cb, int ldc,
    u16* __restrict__ VtOut) {
    constexpr int MI = TM / 32;               // m-subtiles per wave
    __shared__ u16 As[2][TM * 32];
    __shared__ u16 Bs[2][128 * 32];
    const int tid = threadIdx.x;
    const int wid = tid >> 6, lane = tid & 63;
    const int ln = lane & 15, quad = lane >> 4;
    const int bm = blockIdx.y * TM, bn = blockIdx.x * 128;
    const int wm = (wid >> 1) * (TM / 2), wn = (wid & 1) * 64;
    const int lrow = lane >> 2;               // DMA: row within 16-row group
    const int lchunk = (lane & 3) * 8;        // DMA: u16 offset of 16B chunk

    f32x4 acc[MI][4];
#pragma unroll
    for (int i = 0; i < MI; ++i)
#pragma unroll
        for (int j = 0; j < 4; ++j) acc[i][j] = (f32x4){0.f, 0.f, 0.f, 0.f};

    for (int k0 = 0; k0 < 1024; k0 += 64) {
#pragma unroll
        for (int hf = 0; hf < 2; ++hf) {
#pragma unroll
            for (int p = 0; p < TM / 64; ++p) {
                int r = p * 64 + wid * 16;
                glds16(&Af[(bm + r + lrow) * 1024 + k0 + hf * 32 + lchunk],
                       &As[hf][r * 32]);
            }
#pragma unroll
            for (int p = 0; p < 2; ++p) {
                int r = p * 64 + wid * 16;
                glds16(&Bf[(bn + r + lrow) * 1024 + k0 + hf * 32 + lchunk],
                       &Bs[hf][r * 32]);
            }
        }
        asm volatile("s_waitcnt vmcnt(0)" ::: "memory");
        __syncthreads();

        half8 a[MI][2], b[4][2];
#pragma unroll
        for (int kc = 0; kc < 2; ++kc) {
#pragma unroll
            for (int j = 0; j < 4; ++j)
                b[j][kc] = *(const half8*)&Bs[kc][(wn + j * 16 + ln) * 32 + quad * 8];
#pragma unroll
            for (int i = 0; i < MI; ++i)
                a[i][kc] = *(const half8*)&As[kc][(wm + i * 16 + ln) * 32 + quad * 8];
        }
#pragma unroll
        for (int i = 0; i < MI; ++i)
#pragma unroll
            for (int j = 0; j < 4; ++j) {
                acc[i][j] = MFMAH(a[i][0], b[j][0], acc[i][j]);
                acc[i][j] = MFMAH(a[i][1], b[j][1], acc[i][j]);
            }
        __syncthreads();
    }

    if (VtOut && bn >= 2048) {
        // transposed store: VtOut[d][seq]; lane holds 4 consecutive seq rows.
#pragma unroll
        for (int i = 0; i < MI; ++i)
#pragma unroll
            for (int j = 0; j < 4; ++j) {
                int col = bn + wn + j * 16 + ln;
                float bv = bias[col];
                int colV = col - 2048;
                int row0 = bm + wm + i * 16 + quad * 4;
                ushort4 pk = make_ushort4(f2h(acc[i][j][0] + bv), f2h(acc[i][j][1] + bv),
                                          f2h(acc[i][j][2] + bv), f2h(acc[i][j][3] + bv));
                *(ushort4*)&VtOut[colV * 4096 + row0] = pk;
            }
        return;
    }

#pragma unroll
    for (int i = 0; i < MI; ++i)
#pragma unroll
        for (int j = 0; j < 4; ++j) {
            int col = bn + wn + j * 16 + ln;
            float bv = bias[col];
#pragma unroll
            for (int r = 0; r < 4; ++r) {
                int row = bm + wm + i * 16 + quad * 4 + r;
                float v = acc[i][j][r] + bv;
                if (Cb) Cb[row * ldc + col] = f2h(v);
                else    Cf[row * ldc + col] = v;
            }
        }
}

// ============ flash attention, fp16 MFMA, transposed S/O ============
// Block: 4 waves x 32 q-rows = 128 q of one (b,h). 64-key tiles, register-
// prefetch double buffer (1 barrier/tile). Scores in log2 domain (q pre-scaled
// by log2e/8) -> p = v_exp_f32 raw. Row sums via ones-MFMA.
// P buffer: packed [qrow][64] u16 rows with XOR bank swizzle
// (physical 16B-chunk = logical chunk ^ (row&7)) -> conflict-free writes+reads.
__global__ __launch_bounds__(256) void flash_f16(
    const u16* __restrict__ QKV, const u16* __restrict__ Vt,
    u16* __restrict__ AO) {
    __shared__ u16 Ks[2][64 * 72];     // [key][d], stride 72
    __shared__ u16 Vs[2][64 * 72];     // [d][key], stride 72
    __shared__ u16 Ps[4][32 * 64];     // per-wave [qrow][key], packed + swizzled

    const int tid = threadIdx.x;
    const int wid = tid >> 6, lane = tid & 63;
    const int ln = lane & 15, quad = lane >> 4;
    const int qt = blockIdx.x, h = blockIdx.y, b = blockIdx.z;
    const int rowbase = b * NQ;
    const int col0 = h * 64;
    const int q0 = rowbase + qt * 128 + wid * 32;

    const half8 ones = {(f16)1, (f16)1, (f16)1, (f16)1,
                        (f16)1, (f16)1, (f16)1, (f16)1};

    // Q fragments (B-operand: lane ln = q-row q0+mi*16+ln, k = kc*32+quad*8+j)
    half8 qf[2][2];
#pragma unroll
    for (int mi = 0; mi < 2; ++mi)
#pragma unroll
        for (int kc = 0; kc < 2; ++kc)
            qf[mi][kc] = *(const half8*)&QKV[(q0 + mi * 16 + ln) * 3072 + col0 +
                                             kc * 32 + quad * 8];

    f32x4 accO[4][2];    // [a: d-subtile][mi], element (d=a*16+quad*4+r, q=mi*16+ln)
    f32x4 accS[2];       // row sums, col = q = ln
#pragma unroll
    for (int mi = 0; mi < 2; ++mi) {
        accS[mi] = (f32x4){0.f, 0.f, 0.f, 0.f};
#pragma unroll
        for (int a = 0; a < 4; ++a) accO[a][mi] = (f32x4){0.f, 0.f, 0.f, 0.f};
    }

    const int srow = tid >> 2;          // 0..63
    const int sc0 = (tid & 3) * 16;     // 0,16,32,48
    const int NT = NQ / 64;

    // P swizzle helpers (row-local): write chunk = 2a + quad/2, off (quad&1)*4;
    // read chunk = kc*4 + quad. Physical chunk = chunk ^ (ln & 7).
    const int swz = ln & 7;

    // stage tile 0
    {
        const u16* kg = QKV + (rowbase + srow) * 3072 + 1024 + col0;
        const u16* vg = Vt + (col0 + srow) * 4096 + rowbase;
        *(uint4*)&Ks[0][srow * 72 + sc0]     = *(const uint4*)&kg[sc0];
        *(uint4*)&Ks[0][srow * 72 + sc0 + 8] = *(const uint4*)&kg[sc0 + 8];
        *(uint4*)&Vs[0][srow * 72 + sc0]     = *(const uint4*)&vg[sc0];
        *(uint4*)&Vs[0][srow * 72 + sc0 + 8] = *(const uint4*)&vg[sc0 + 8];
    }
    __syncthreads();

    for (int kt = 0; kt < NT; ++kt) {
        const int cur = kt & 1;
        uint4 nk0, nk1, nv0, nv1;
        if (kt + 1 < NT) {
            const u16* kg = QKV + (rowbase + (kt + 1) * 64 + srow) * 3072 + 1024 + col0;
            const u16* vg = Vt + (col0 + srow) * 4096 + rowbase + (kt + 1) * 64;
            nk0 = *(const uint4*)&kg[sc0];
            nk1 = *(const uint4*)&kg[sc0 + 8];
            nv0 = *(const uint4*)&vg[sc0];
            nv1 = *(const uint4*)&vg[sc0 + 8];
        }

        // S^T = K @ Q^T : element (key = a*16+quad*4+r, q = mi*16+ln)
        f32x4 s[4][2];
#pragma unroll
        for (int a = 0; a < 4; ++a) {
            half8 kf0 = *(const half8*)&Ks[cur][(a * 16 + ln) * 72 + quad * 8];
            half8 kf1 = *(const half8*)&Ks[cur][(a * 16 + ln) * 72 + 32 + quad * 8];
#pragma unroll
            for (int mi = 0; mi < 2; ++mi) {
                f32x4 t = (f32x4){0.f, 0.f, 0.f, 0.f};
                t = MFMAH(kf0, qf[mi][0], t);
                t = MFMAH(kf1, qf[mi][1], t);
                s[a][mi] = t;
            }
        }

        // p = 2^s: one 8B swizzled LDS write per (mi,a)
#pragma unroll
        for (int mi = 0; mi < 2; ++mi)
#pragma unroll
            for (int a = 0; a < 4; ++a) {
                float p0 = fexp2(s[a][mi][0]), p1 = fexp2(s[a][mi][1]);
                float p2 = fexp2(s[a][mi][2]), p3 = fexp2(s[a][mi][3]);
                uint2 w = make_uint2(pk_h2(p0, p1), pk_h2(p2, p3));
                int chunk = 2 * a + (quad >> 1);
                int addr = (mi * 16 + ln) * 64 + ((chunk ^ swz) << 3) + ((quad & 1) << 2);
                *(uint2*)&Ps[wid][addr] = w;
            }

        asm volatile("s_waitcnt lgkmcnt(0)" ::: "memory");   // P visible wave-wide

        // P fragments (B-operand, swizzled b128 reads) + row sums via ones-MFMA
        half8 pf[2][2];
#pragma unroll
        for (int mi = 0; mi < 2; ++mi)
#pragma unroll
            for (int kc = 0; kc < 2; ++kc) {
                int chunk = kc * 4 + quad;
                pf[mi][kc] = *(const half8*)&Ps[wid][(mi * 16 + ln) * 64 +
                                                     ((chunk ^ swz) << 3)];
                accS[mi] = MFMAH(ones, pf[mi][kc], accS[mi]);
            }

        // O^T += V^T @ P^T : element (d = a*16+quad*4+r, q = mi*16+ln)
#pragma unroll
        for (int a = 0; a < 4; ++a) {
            half8 vf0 = *(const half8*)&Vs[cur][(a * 16 + ln) * 72 + quad * 8];
            half8 vf1 = *(const half8*)&Vs[cur][(a * 16 + ln) * 72 + 32 + quad * 8];
#pragma unroll
            for (int mi = 0; mi < 2; ++mi) {
                accO[a][mi] = MFMAH(vf0, pf[mi][0], accO[a][mi]);
                accO[a][mi] = MFMAH(vf1, pf[mi][1], accO[a][mi]);
            }
        }

        if (kt + 1 < NT) {
            const int nb = cur ^ 1;
            *(uint4*)&Ks[nb][srow * 72 + sc0]     = nk0;
            *(uint4*)&Ks[nb][srow * 72 + sc0 + 8] = nk1;
            *(uint4*)&Vs[nb][srow * 72 + sc0]     = nv0;
            *(uint4*)&Vs[nb][srow * 72 + sc0 + 8] = nv1;
        }
        __syncthreads();
    }

    // epilogue: normalize (inv uniform per lane), single fp16 AO, ushort4 stores
#pragma unroll
    for (int mi = 0; mi < 2; ++mi) {
        float inv = 1.f / accS[mi][0];
        int q = q0 + mi * 16 + ln;
#pragma unroll
        for (int a = 0; a < 4; ++a) {
            ushort4 pk = make_ushort4(f2h(accO[a][mi][0] * inv),
                                      f2h(accO[a][mi][1] * inv),
                                      f2h(accO[a][mi][2] * inv),
                                      f2h(accO[a][mi][3] * inv));
            *(ushort4*)&AO[q * 1024 + col0 + a * 16 + quad * 4] = pk;
        }
    }
}

// ============ launch ============
extern "C" void kernel_launch(void* const* d_in, const int* in_sizes, int n_in,
                              void* d_out, int out_size, void* d_ws, size_t ws_size,
                              hipStream_t stream) {
    const float* x = (const float*)d_in[0];
    const float* w[4]  = {(const float*)d_in[1],  (const float*)d_in[5],
                          (const float*)d_in[9],  (const float*)d_in[13]};
    const float* bv[4] = {(const float*)d_in[2],  (const float*)d_in[6],
                          (const float*)d_in[10], (const float*)d_in[14]};
    const float* dw[4] = {(const float*)d_in[3],  (const float*)d_in[7],
                          (const float*)d_in[11], (const float*)d_in[15]};
    const float* db[4] = {(const float*)d_in[4],  (const float*)d_in[8],
                          (const float*)d_in[12], (const float*)d_in[16]};

    u16* p = (u16*)d_ws;
    u16* Wf  = p; p += 4096 * 1024;
    u16* xf  = p; p += 4096 * 1024;
    u16* QKV = p; p += 4096 * 3072;   // V third unused (lives in Vt)
    u16* Vt  = p; p += 1024 * 4096;
    float* ball = (float*)p;          // 4096 floats
    // AO aliases xf: x is dead after the QKV GEMM completes (same stream).
    u16* AO = xf;

    merge_w16<<<16384, 256, 0, stream>>>(w[0], dw[0], db[0], w[1], dw[1], db[1],
                                         w[2], dw[2], db[2], w[3], dw[3], db[3], Wf);
    bias_pack<<<16, 256, 0, stream>>>(bv[0], bv[1], bv[2], bv[3], ball);
    xcast<<<4096, 256, 0, stream>>>(x, xf);

    // fused q,k,v projection: q,k -> QKV fp16 row-major; v -> Vt transposed
    gemm_f16<128><<<dim3(24, 32), 256, 0, stream>>>(xf, Wf, ball,
                                                    nullptr, QKV, 3072, Vt);

    flash_f16<<<dim3(NQ / 128, 16, NB), 256, 0, stream>>>(QKV, Vt, AO);

    // o projection: fp32 out, TM=64 -> 512 blocks (2 blocks/CU)
    gemm_f16<64><<<dim3(8, 64), 256, 0, stream>>>(AO, Wf + 3072 * 1024,
                                                  ball + 3072, (float*)d_out, nullptr, 1024,
                                                  nullptr);
}